// Round 1
// baseline (483.216 us; speedup 1.0000x reference)
//
#include <hip/hip_runtime.h>
#include <math.h>

#define BATCH 4096
#define FEAT  1024
#define EDIM  16
#define NDOM  8
#define TDIM  1040   // FEAT + EDIM
#define NLAYER 3
#define EPSV  1e-5f

#define BM 64
#define BN 64
#define BK 16

// ---------------- grouping: histogram + scatter rows by domain ----------------
__global__ __launch_bounds__(256) void group_kernel(const int* __restrict__ dom,
                                                    int* __restrict__ perm,
                                                    int* __restrict__ starts) {
    __shared__ int cnt[NDOM];
    __shared__ int off[NDOM];
    int t = threadIdx.x;
    if (t < NDOM) cnt[t] = 0;
    __syncthreads();
    for (int b = t; b < BATCH; b += blockDim.x) atomicAdd(&cnt[dom[b]], 1);
    __syncthreads();
    if (t == 0) {
        int s = 0;
        for (int d = 0; d < NDOM; d++) { off[d] = s; starts[d] = s; s += cnt[d]; }
        starts[NDOM] = s;
    }
    __syncthreads();
    for (int b = t; b < BATCH; b += blockDim.x) {
        int p = atomicAdd(&off[dom[b]], 1);
        perm[p] = b;
    }
}

// ------- per-row: LayerNorm + domain affine + concat + cross net + aux net -------
__global__ __launch_bounds__(256) void prep_kernel(
    const float* __restrict__ x, const int* __restrict__ dom,
    const float* __restrict__ pnw, const float* __restrict__ pnb,
    const float* __restrict__ demb,
    const float* __restrict__ crw, const float* __restrict__ crb,
    const float* __restrict__ aW1, const float* __restrict__ ab1,
    const float* __restrict__ aW2, const float* __restrict__ ab2,
    const int* __restrict__ perm,
    float* __restrict__ XCg, float* __restrict__ auxg) {
    __shared__ float x0s[TDIM];
    __shared__ float xcs[TDIM];
    __shared__ float redS[4];
    __shared__ float redQ[4];
    __shared__ float sMean, sRstd;

    int p = blockIdx.x;
    int row = perm[p];
    int d = dom[row];
    int t = threadIdx.x;

    // load 4 contiguous floats of this row
    float4 v = *(const float4*)(x + (size_t)row * FEAT + 4 * t);
    float s  = v.x + v.y + v.z + v.w;
    float ss = v.x*v.x + v.y*v.y + v.z*v.z + v.w*v.w;
    #pragma unroll
    for (int o = 32; o > 0; o >>= 1) {
        s  += __shfl_down(s,  o);
        ss += __shfl_down(ss, o);
    }
    if ((t & 63) == 0) { redS[t >> 6] = s; redQ[t >> 6] = ss; }
    __syncthreads();
    if (t == 0) {
        float S = redS[0] + redS[1] + redS[2] + redS[3];
        float Q = redQ[0] + redQ[1] + redQ[2] + redQ[3];
        float mean = S / (float)FEAT;
        float var  = Q / (float)FEAT - mean * mean;
        sMean = mean;
        sRstd = rsqrtf(var + EPSV);
    }
    __syncthreads();
    float mean = sMean, rstd = sRstd;

    float4 wv = *(const float4*)(pnw + (size_t)d * FEAT + 4 * t);
    float4 bv = *(const float4*)(pnb + (size_t)d * FEAT + 4 * t);
    {
        float n0 = (v.x - mean) * rstd * wv.x + bv.x;
        float n1 = (v.y - mean) * rstd * wv.y + bv.y;
        float n2 = (v.z - mean) * rstd * wv.z + bv.z;
        float n3 = (v.w - mean) * rstd * wv.w + bv.w;
        int j = 4 * t;
        x0s[j+0] = n0; x0s[j+1] = n1; x0s[j+2] = n2; x0s[j+3] = n3;
        xcs[j+0] = n0; xcs[j+1] = n1; xcs[j+2] = n2; xcs[j+3] = n3;
    }
    if (t < EDIM) {
        float e = demb[d * EDIM + t];
        x0s[FEAT + t] = e;
        xcs[FEAT + t] = e;
    }
    __syncthreads();

    // cross layers: proj = dot(xc, w_l); xc = x0*proj + b_l + xc
    for (int l = 0; l < NLAYER; l++) {
        float partial = 0.f;
        for (int j = t; j < TDIM; j += 256) partial += xcs[j] * crw[l * TDIM + j];
        #pragma unroll
        for (int o = 32; o > 0; o >>= 1) partial += __shfl_down(partial, o);
        if ((t & 63) == 0) redS[t >> 6] = partial;
        __syncthreads();
        float proj = redS[0] + redS[1] + redS[2] + redS[3];
        for (int j = t; j < TDIM; j += 256)
            xcs[j] = x0s[j] * proj + crb[l * TDIM + j] + xcs[j];
        __syncthreads();
    }

    // write permuted xc row
    for (int j = t; j < TDIM; j += 256) XCg[(size_t)p * TDIM + j] = xcs[j];

    // aux net: relu(xd @ aW1 + ab1) @ aW2 + ab2  (xd = x0s[FEAT..FEAT+16))
    if (t < 32) {
        float h = ab1[t];
        #pragma unroll
        for (int e = 0; e < EDIM; e++) h += x0s[FEAT + e] * aW1[e * 32 + t];
        h = fmaxf(h, 0.f);
        float c = h * aW2[t];
        #pragma unroll
        for (int o = 16; o > 0; o >>= 1) c += __shfl_down(c, o, 32);
        if (t == 0) auxg[p] = c + ab2[0];
    }
}

// ---------------- fused tiled GEMM: z=0 center chain, z=1 domain chains ----------------
__global__ __launch_bounds__(256) void gemm_fused(
    const float* __restrict__ Ac, const float* __restrict__ Ad, int lda,
    const float* __restrict__ Wc, const float* __restrict__ Wd,
    const float* __restrict__ bc, const float* __restrict__ bd,
    float* __restrict__ Cc, float* __restrict__ Cd,
    const int* __restrict__ starts,
    int K, int N, int relu) {
    __shared__ float As[BK][BM + 1];
    __shared__ float Bs[BK][BN];

    const float* A; const float* W; const float* bias; float* Cmat;
    int m0, mEnd;
    if (blockIdx.z == 0) {
        if ((int)blockIdx.y >= BATCH / BM) return;
        A = Ac; W = Wc; bias = bc; Cmat = Cc;
        m0 = blockIdx.y * BM; mEnd = BATCH;
    } else {
        const int slots = BATCH / BM;               // 64
        int d = blockIdx.y / slots, s = blockIdx.y % slots;
        int ds = starts[d], de = starts[d + 1];
        m0 = ds + s * BM;
        if (m0 >= de) return;
        mEnd = de;
        A = Ad; W = Wd + (size_t)d * K * N; bias = bd + d * N; Cmat = Cd;
    }
    int n0 = blockIdx.x * BN;
    int tid = threadIdx.x;
    int tx = tid & 15, ty = tid >> 4;

    int am = tid >> 2;            // 0..63
    int ak = (tid & 3) * 4;       // 0,4,8,12
    int bk = tid >> 4;            // 0..15
    int bn = (tid & 15) * 4;      // 0..60

    float acc[4][4] = {{0.f}};

    for (int k0 = 0; k0 < K; k0 += BK) {
        float4 av;
        if (m0 + am < mEnd) av = *(const float4*)(A + (size_t)(m0 + am) * lda + k0 + ak);
        else                av = make_float4(0.f, 0.f, 0.f, 0.f);
        As[ak + 0][am] = av.x; As[ak + 1][am] = av.y;
        As[ak + 2][am] = av.z; As[ak + 3][am] = av.w;

        float4 bvv = *(const float4*)(W + (size_t)(k0 + bk) * N + n0 + bn);
        *(float4*)&Bs[bk][bn] = bvv;
        __syncthreads();

        #pragma unroll
        for (int k = 0; k < BK; k++) {
            float a[4], b[4];
            #pragma unroll
            for (int i = 0; i < 4; i++) a[i] = As[k][ty * 4 + i];
            #pragma unroll
            for (int j = 0; j < 4; j++) b[j] = Bs[k][tx * 4 + j];
            #pragma unroll
            for (int i = 0; i < 4; i++)
                #pragma unroll
                for (int j = 0; j < 4; j++)
                    acc[i][j] = fmaf(a[i], b[j], acc[i][j]);
        }
        __syncthreads();
    }

    #pragma unroll
    for (int i = 0; i < 4; i++) {
        int m = m0 + ty * 4 + i;
        if (m >= mEnd) continue;
        float4 o;
        int n = n0 + tx * 4;
        o.x = acc[i][0] + bias[n + 0];
        o.y = acc[i][1] + bias[n + 1];
        o.z = acc[i][2] + bias[n + 2];
        o.w = acc[i][3] + bias[n + 3];
        if (relu) {
            o.x = fmaxf(o.x, 0.f); o.y = fmaxf(o.y, 0.f);
            o.z = fmaxf(o.z, 0.f); o.w = fmaxf(o.w, 0.f);
        }
        *(float4*)(Cmat + (size_t)m * N + n) = o;
    }
}

// ---------------- final: STAR fusion + 128->64->1 MLP + aux + sigmoid ----------------
__global__ __launch_bounds__(256) void final_kernel(
    const float* __restrict__ Hc, const float* __restrict__ Hd,
    const float* __restrict__ fW1, const float* __restrict__ fb1,
    const float* __restrict__ fW2, const float* __restrict__ fb2,
    const float* __restrict__ auxg, const int* __restrict__ perm,
    float* __restrict__ out) {
    __shared__ float fused[4][128];
    int tid = threadIdx.x;
    int sub = tid >> 6, lane = tid & 63;
    int p = blockIdx.x * 4 + sub;

    for (int j = lane; j < 128; j += 64)
        fused[sub][j] = Hc[(size_t)p * 128 + j] * tanhf(Hd[(size_t)p * 128 + j]);
    __syncthreads();

    float h = fb1[lane];
    #pragma unroll 8
    for (int j = 0; j < 128; j++) h = fmaf(fused[sub][j], fW1[j * 64 + lane], h);
    h = fmaxf(h, 0.f);
    float c = h * fW2[lane];
    #pragma unroll
    for (int o = 32; o > 0; o >>= 1) c += __shfl_down(c, o);
    if (lane == 0) {
        float logit = c + fb2[0] + auxg[p];
        out[perm[p]] = 1.f / (1.f + expf(-logit));
    }
}

extern "C" void kernel_launch(void* const* d_in, const int* in_sizes, int n_in,
                              void* d_out, int out_size, void* d_ws, size_t ws_size,
                              hipStream_t stream) {
    (void)in_sizes; (void)n_in; (void)out_size; (void)ws_size;

    const float* x    = (const float*)d_in[0];
    const int*   dom  = (const int*)  d_in[1];
    const float* pnw  = (const float*)d_in[2];
    const float* pnb  = (const float*)d_in[3];
    const float* demb = (const float*)d_in[4];
    const float* crw  = (const float*)d_in[5];
    const float* crb  = (const float*)d_in[6];
    const float* cW1  = (const float*)d_in[7];
    const float* cb1  = (const float*)d_in[8];
    const float* cW2  = (const float*)d_in[9];
    const float* cb2  = (const float*)d_in[10];
    const float* cW3  = (const float*)d_in[11];
    const float* cb3  = (const float*)d_in[12];
    const float* dW1  = (const float*)d_in[13];
    const float* db1  = (const float*)d_in[14];
    const float* dW2  = (const float*)d_in[15];
    const float* db2  = (const float*)d_in[16];
    const float* dW3  = (const float*)d_in[17];
    const float* db3  = (const float*)d_in[18];
    const float* fW1  = (const float*)d_in[19];
    const float* fb1  = (const float*)d_in[20];
    const float* fW2  = (const float*)d_in[21];
    const float* fb2  = (const float*)d_in[22];
    const float* aW1  = (const float*)d_in[23];
    const float* ab1  = (const float*)d_in[24];
    const float* aW2  = (const float*)d_in[25];
    const float* ab2  = (const float*)d_in[26];
    float* out = (float*)d_out;

    // workspace layout
    int*   perm   = (int*)d_ws;                       // BATCH ints
    int*   starts = perm + BATCH;                     // NDOM+1 ints
    float* wsf    = (float*)d_ws;
    size_t off = 4352;                                // 16B-aligned float offset past the ints
    float* XCg  = wsf + off;  off += (size_t)BATCH * TDIM;
    float* H1c  = wsf + off;  off += (size_t)BATCH * 512;
    float* H1d  = wsf + off;  off += (size_t)BATCH * 512;
    float* H2c  = wsf + off;  off += (size_t)BATCH * 256;
    float* H2d  = wsf + off;  off += (size_t)BATCH * 256;
    float* H3c  = wsf + off;  off += (size_t)BATCH * 128;
    float* H3d  = wsf + off;  off += (size_t)BATCH * 128;
    float* auxg = wsf + off;  off += BATCH;

    group_kernel<<<1, 256, 0, stream>>>(dom, perm, starts);

    prep_kernel<<<BATCH, 256, 0, stream>>>(x, dom, pnw, pnb, demb, crw, crb,
                                           aW1, ab1, aW2, ab2, perm, XCg, auxg);

    // L1: (B x 1040) @ (1040 x 512), relu
    gemm_fused<<<dim3(512 / BN, NDOM * (BATCH / BM), 2), 256, 0, stream>>>(
        XCg, XCg, TDIM, cW1, dW1, cb1, db1, H1c, H1d, starts, TDIM, 512, 1);
    // L2: (B x 512) @ (512 x 256), relu
    gemm_fused<<<dim3(256 / BN, NDOM * (BATCH / BM), 2), 256, 0, stream>>>(
        H1c, H1d, 512, cW2, dW2, cb2, db2, H2c, H2d, starts, 512, 256, 1);
    // L3: (B x 256) @ (256 x 128), no relu
    gemm_fused<<<dim3(128 / BN, NDOM * (BATCH / BM), 2), 256, 0, stream>>>(
        H2c, H2d, 256, cW3, dW3, cb3, db3, H3c, H3d, starts, 256, 128, 0);

    final_kernel<<<BATCH / 4, 256, 0, stream>>>(H3c, H3d, fW1, fb1, fW2, fb2,
                                                auxg, perm, out);
}

// Round 2
// 249.880 us; speedup vs baseline: 1.9338x; 1.9338x over previous
//
#include <hip/hip_runtime.h>
#include <math.h>

#define BATCH 4096
#define FEAT  1024
#define EDIM  16
#define NDOM  8
#define TDIM  1040   // FEAT + EDIM
#define KP1   1088   // TDIM padded to multiple of 64
#define NLAYER 3
#define EPSV  1e-5f

typedef __attribute__((ext_vector_type(8))) short bf16x8;
typedef __attribute__((ext_vector_type(4))) float f32x4;

__device__ __forceinline__ unsigned short f2bf(float f) {
    union { float f; unsigned int u; } v; v.f = f;
    unsigned int u = v.u;
    return (unsigned short)((u + 0x7fffu + ((u >> 16) & 1u)) >> 16);
}

// ---------------- grouping: histogram + scatter rows by domain ----------------
__global__ __launch_bounds__(256) void group_kernel(const int* __restrict__ dom,
                                                    int* __restrict__ perm,
                                                    int* __restrict__ starts) {
    __shared__ int cnt[NDOM];
    __shared__ int off[NDOM];
    int t = threadIdx.x;
    if (t < NDOM) cnt[t] = 0;
    __syncthreads();
    for (int b = t; b < BATCH; b += blockDim.x) atomicAdd(&cnt[dom[b]], 1);
    __syncthreads();
    if (t == 0) {
        int s = 0;
        for (int d = 0; d < NDOM; d++) { off[d] = s; starts[d] = s; s += cnt[d]; }
        starts[NDOM] = s;
    }
    __syncthreads();
    for (int b = t; b < BATCH; b += blockDim.x) {
        int p = atomicAdd(&off[dom[b]], 1);
        perm[p] = b;
    }
}

// ------- weight convert: fp32 (K,N) row-major -> bf16 (N,Kp) row-major, zero-pad K..Kp -------
// grid: (Kp/32, N/32, D); block 256
__global__ __launch_bounds__(256) void convert_w(const float* __restrict__ in,
                                                 unsigned short* __restrict__ out,
                                                 int K, int N, int Kp) {
    __shared__ float tile[32][33];
    int tx = threadIdx.x & 31, ty = threadIdx.x >> 5;   // 32 x 8
    int k0 = blockIdx.x * 32, n0 = blockIdx.y * 32;
    const float* src = in + (size_t)blockIdx.z * K * N;
    unsigned short* dst = out + (size_t)blockIdx.z * N * Kp;
    #pragma unroll
    for (int i = 0; i < 4; i++) {
        int k = k0 + ty + i * 8;
        float v = (k < K) ? src[(size_t)k * N + n0 + tx] : 0.f;
        tile[ty + i * 8][tx] = v;
    }
    __syncthreads();
    #pragma unroll
    for (int i = 0; i < 4; i++) {
        int n = n0 + ty + i * 8;
        dst[(size_t)n * Kp + k0 + tx] = f2bf(tile[tx][ty + i * 8]);
    }
}

// ------- per-row: LayerNorm + domain affine + concat + cross net + aux net -------
__global__ __launch_bounds__(256) void prep_kernel(
    const float* __restrict__ x, const int* __restrict__ dom,
    const float* __restrict__ pnw, const float* __restrict__ pnb,
    const float* __restrict__ demb,
    const float* __restrict__ crw, const float* __restrict__ crb,
    const float* __restrict__ aW1, const float* __restrict__ ab1,
    const float* __restrict__ aW2, const float* __restrict__ ab2,
    const int* __restrict__ perm,
    unsigned short* __restrict__ XCb, float* __restrict__ auxg) {
    __shared__ float x0s[TDIM];
    __shared__ float xcs[TDIM];
    __shared__ float redS[4];
    __shared__ float redQ[4];
    __shared__ float sMean, sRstd;

    int p = blockIdx.x;
    int row = perm[p];
    int d = dom[row];
    int t = threadIdx.x;

    float4 v = *(const float4*)(x + (size_t)row * FEAT + 4 * t);
    float s  = v.x + v.y + v.z + v.w;
    float ss = v.x*v.x + v.y*v.y + v.z*v.z + v.w*v.w;
    #pragma unroll
    for (int o = 32; o > 0; o >>= 1) {
        s  += __shfl_down(s,  o);
        ss += __shfl_down(ss, o);
    }
    if ((t & 63) == 0) { redS[t >> 6] = s; redQ[t >> 6] = ss; }
    __syncthreads();
    if (t == 0) {
        float S = redS[0] + redS[1] + redS[2] + redS[3];
        float Q = redQ[0] + redQ[1] + redQ[2] + redQ[3];
        float mean = S / (float)FEAT;
        float var  = Q / (float)FEAT - mean * mean;
        sMean = mean;
        sRstd = rsqrtf(var + EPSV);
    }
    __syncthreads();
    float mean = sMean, rstd = sRstd;

    float4 wv = *(const float4*)(pnw + (size_t)d * FEAT + 4 * t);
    float4 bv = *(const float4*)(pnb + (size_t)d * FEAT + 4 * t);
    {
        float n0 = (v.x - mean) * rstd * wv.x + bv.x;
        float n1 = (v.y - mean) * rstd * wv.y + bv.y;
        float n2 = (v.z - mean) * rstd * wv.z + bv.z;
        float n3 = (v.w - mean) * rstd * wv.w + bv.w;
        int j = 4 * t;
        x0s[j+0] = n0; x0s[j+1] = n1; x0s[j+2] = n2; x0s[j+3] = n3;
        xcs[j+0] = n0; xcs[j+1] = n1; xcs[j+2] = n2; xcs[j+3] = n3;
    }
    if (t < EDIM) {
        float e = demb[d * EDIM + t];
        x0s[FEAT + t] = e;
        xcs[FEAT + t] = e;
    }
    __syncthreads();

    for (int l = 0; l < NLAYER; l++) {
        float partial = 0.f;
        for (int j = t; j < TDIM; j += 256) partial += xcs[j] * crw[l * TDIM + j];
        #pragma unroll
        for (int o = 32; o > 0; o >>= 1) partial += __shfl_down(partial, o);
        if ((t & 63) == 0) redS[t >> 6] = partial;
        __syncthreads();
        float proj = redS[0] + redS[1] + redS[2] + redS[3];
        for (int j = t; j < TDIM; j += 256)
            xcs[j] = x0s[j] * proj + crb[l * TDIM + j] + xcs[j];
        __syncthreads();
    }

    // write permuted xc row (bf16, K padded to 1088 with zeros)
    for (int j = t; j < TDIM; j += 256) XCb[(size_t)p * KP1 + j] = f2bf(xcs[j]);
    if (t < KP1 - TDIM) XCb[(size_t)p * KP1 + TDIM + t] = 0;

    if (t < 32) {
        float h = ab1[t];
        #pragma unroll
        for (int e = 0; e < EDIM; e++) h += x0s[FEAT + e] * aW1[e * 32 + t];
        h = fmaxf(h, 0.f);
        float c = h * aW2[t];
        #pragma unroll
        for (int o = 16; o > 0; o >>= 1) c += __shfl_down(c, o, 32);
        if (t == 0) auxg[p] = c + ab2[0];
    }
}

// ---------------- MFMA bf16 GEMM, fused center+domain ----------------
// A: bf16 row-major (rows x lda). W: bf16 (N x Kp) row-major. C: N-major.
// grid.x = N/64; grid.y = 32 + NDOM*32  (center slots then domain slots)
__global__ __launch_bounds__(256) void gemm_mfma(
    const unsigned short* __restrict__ Ac, const unsigned short* __restrict__ Ad, int lda,
    const unsigned short* __restrict__ Wc, const unsigned short* __restrict__ Wd,
    const float* __restrict__ bc, const float* __restrict__ bd,
    unsigned short* __restrict__ Cbc, unsigned short* __restrict__ Cbd,
    float* __restrict__ Cfc, float* __restrict__ Cfd,
    const int* __restrict__ starts,
    int Kp, int N, int relu, int outBf) {
    __shared__ short As[128 * 64];   // swizzled [m][k] chunks
    __shared__ short Bs[64 * 64];    // swizzled [n][k] chunks

    const unsigned short* A; const unsigned short* W; const float* bias;
    unsigned short* Cb; float* Cf;
    int m0, mEnd;
    int y = blockIdx.y;
    if (y < 32) {
        A = Ac; W = Wc; bias = bc; Cb = Cbc; Cf = Cfc;
        m0 = y * 128; mEnd = BATCH;
    } else {
        int yy = y - 32;
        int d = yy >> 5, sl = yy & 31;
        int ds = starts[d], de = starts[d + 1];
        m0 = ds + sl * 128;
        if (m0 >= de) return;
        mEnd = de;
        A = Ad; W = Wd + (size_t)d * N * Kp; bias = bd + d * N; Cb = Cbd; Cf = Cfd;
    }
    int n0 = blockIdx.x * 64;
    int tid = threadIdx.x;
    int w = tid >> 6, lane = tid & 63;
    int wm = w >> 1, wn = w & 1;
    int lr = lane & 15, q = lane >> 4;

    f32x4 acc[4][2];
    #pragma unroll
    for (int i = 0; i < 4; i++)
        #pragma unroll
        for (int j = 0; j < 2; j++)
            acc[i][j] = (f32x4){0.f, 0.f, 0.f, 0.f};

    const uint4 zero16 = make_uint4(0u, 0u, 0u, 0u);

    for (int k0 = 0; k0 < Kp; k0 += 64) {
        // stage A: 128 rows x 64 k (bf16) = 1024 chunks of 16B
        #pragma unroll
        for (int i = 0; i < 4; i++) {
            int flat = tid + i * 256;
            int m = flat >> 3, c = flat & 7;
            int row = m0 + m;
            uint4 val = (row < mEnd)
                ? *(const uint4*)(A + (size_t)row * lda + k0 + c * 8)
                : zero16;
            *(uint4*)(As + m * 64 + ((c ^ (m & 7)) * 8)) = val;
        }
        // stage B: 64 rows (n) x 64 k = 512 chunks
        #pragma unroll
        for (int i = 0; i < 2; i++) {
            int flat = tid + i * 256;
            int n = flat >> 3, c = flat & 7;
            uint4 val = *(const uint4*)(W + (size_t)(n0 + n) * Kp + k0 + c * 8);
            *(uint4*)(Bs + n * 64 + ((c ^ (n & 7)) * 8)) = val;
        }
        __syncthreads();

        #pragma unroll
        for (int half = 0; half < 2; half++) {
            bf16x8 af[4], bf[2];
            #pragma unroll
            for (int i = 0; i < 4; i++) {
                int m = wm * 64 + i * 16 + lr;
                int c = half * 4 + q;
                af[i] = *(const bf16x8*)(As + m * 64 + ((c ^ (m & 7)) * 8));
            }
            #pragma unroll
            for (int j = 0; j < 2; j++) {
                int n = wn * 32 + j * 16 + lr;
                int c = half * 4 + q;
                bf[j] = *(const bf16x8*)(Bs + n * 64 + ((c ^ (n & 7)) * 8));
            }
            #pragma unroll
            for (int i = 0; i < 4; i++)
                #pragma unroll
                for (int j = 0; j < 2; j++)
                    acc[i][j] = __builtin_amdgcn_mfma_f32_16x16x32_bf16(
                        af[i], bf[j], acc[i][j], 0, 0, 0);
        }
        __syncthreads();
    }

    // epilogue: C[row][col], row = m0+wm*64+i*16+q*4+r, col = n0+wn*32+j*16+lr
    #pragma unroll
    for (int i = 0; i < 4; i++) {
        #pragma unroll
        for (int j = 0; j < 2; j++) {
            int col = n0 + wn * 32 + j * 16 + lr;
            float bv = bias[col];
            int rowb = m0 + wm * 64 + i * 16 + q * 4;
            #pragma unroll
            for (int r = 0; r < 4; r++) {
                int row = rowb + r;
                if (row >= mEnd) continue;
                float val = acc[i][j][r] + bv;
                if (relu) val = fmaxf(val, 0.f);
                if (outBf) Cb[(size_t)row * N + col] = f2bf(val);
                else       Cf[(size_t)row * N + col] = val;
            }
        }
    }
}

// ---------------- final: STAR fusion + 128->64->1 MLP + aux + sigmoid ----------------
__global__ __launch_bounds__(256) void final_kernel(
    const float* __restrict__ Hc, const float* __restrict__ Hd,
    const float* __restrict__ fW1, const float* __restrict__ fb1,
    const float* __restrict__ fW2, const float* __restrict__ fb2,
    const float* __restrict__ auxg, const int* __restrict__ perm,
    float* __restrict__ out) {
    __shared__ float fused[4][128];
    int tid = threadIdx.x;
    int sub = tid >> 6, lane = tid & 63;
    int p = blockIdx.x * 4 + sub;

    for (int j = lane; j < 128; j += 64)
        fused[sub][j] = Hc[(size_t)p * 128 + j] * tanhf(Hd[(size_t)p * 128 + j]);
    __syncthreads();

    float h = fb1[lane];
    #pragma unroll 8
    for (int j = 0; j < 128; j++) h = fmaf(fused[sub][j], fW1[j * 64 + lane], h);
    h = fmaxf(h, 0.f);
    float c = h * fW2[lane];
    #pragma unroll
    for (int o = 32; o > 0; o >>= 1) c += __shfl_down(c, o);
    if (lane == 0) {
        float logit = c + fb2[0] + auxg[p];
        out[perm[p]] = 1.f / (1.f + expf(-logit));
    }
}

extern "C" void kernel_launch(void* const* d_in, const int* in_sizes, int n_in,
                              void* d_out, int out_size, void* d_ws, size_t ws_size,
                              hipStream_t stream) {
    (void)in_sizes; (void)n_in; (void)out_size; (void)ws_size;

    const float* x    = (const float*)d_in[0];
    const int*   dom  = (const int*)  d_in[1];
    const float* pnw  = (const float*)d_in[2];
    const float* pnb  = (const float*)d_in[3];
    const float* demb = (const float*)d_in[4];
    const float* crw  = (const float*)d_in[5];
    const float* crb  = (const float*)d_in[6];
    const float* cW1  = (const float*)d_in[7];
    const float* cb1  = (const float*)d_in[8];
    const float* cW2  = (const float*)d_in[9];
    const float* cb2  = (const float*)d_in[10];
    const float* cW3  = (const float*)d_in[11];
    const float* cb3  = (const float*)d_in[12];
    const float* dW1  = (const float*)d_in[13];
    const float* db1  = (const float*)d_in[14];
    const float* dW2  = (const float*)d_in[15];
    const float* db2  = (const float*)d_in[16];
    const float* dW3  = (const float*)d_in[17];
    const float* db3  = (const float*)d_in[18];
    const float* fW1  = (const float*)d_in[19];
    const float* fb1  = (const float*)d_in[20];
    const float* fW2  = (const float*)d_in[21];
    const float* fb2  = (const float*)d_in[22];
    const float* aW1  = (const float*)d_in[23];
    const float* ab1  = (const float*)d_in[24];
    const float* aW2  = (const float*)d_in[25];
    const float* ab2  = (const float*)d_in[26];
    float* out = (float*)d_out;

    // ---- workspace layout (bytes) ----
    char* base = (char*)d_ws;
    size_t o = 0;
    auto alloc = [&](size_t bytes) { char* p = base + o; o += (bytes + 255) & ~size_t(255); return p; };

    int* perm   = (int*)alloc(BATCH * 4);
    int* starts = (int*)alloc((NDOM + 1) * 4);
    float* auxg = (float*)alloc(BATCH * 4);
    float* H3c  = (float*)alloc((size_t)BATCH * 128 * 4);
    float* H3d  = (float*)alloc((size_t)BATCH * 128 * 4);
    unsigned short* XCb  = (unsigned short*)alloc((size_t)BATCH * KP1 * 2);
    unsigned short* H1c  = (unsigned short*)alloc((size_t)BATCH * 512 * 2);
    unsigned short* H1d  = (unsigned short*)alloc((size_t)BATCH * 512 * 2);
    unsigned short* H2c  = (unsigned short*)alloc((size_t)BATCH * 256 * 2);
    unsigned short* H2d  = (unsigned short*)alloc((size_t)BATCH * 256 * 2);
    unsigned short* Wc1b = (unsigned short*)alloc((size_t)512 * KP1 * 2);
    unsigned short* Wd1b = (unsigned short*)alloc((size_t)NDOM * 512 * KP1 * 2);
    unsigned short* Wc2b = (unsigned short*)alloc((size_t)256 * 512 * 2);
    unsigned short* Wd2b = (unsigned short*)alloc((size_t)NDOM * 256 * 512 * 2);
    unsigned short* Wc3b = (unsigned short*)alloc((size_t)128 * 256 * 2);
    unsigned short* Wd3b = (unsigned short*)alloc((size_t)NDOM * 128 * 256 * 2);

    group_kernel<<<1, 256, 0, stream>>>(dom, perm, starts);

    // weight conversions (transpose to (N,Kp) bf16)
    convert_w<<<dim3(KP1 / 32, 512 / 32, 1),    256, 0, stream>>>(cW1, Wc1b, TDIM, 512, KP1);
    convert_w<<<dim3(KP1 / 32, 512 / 32, NDOM), 256, 0, stream>>>(dW1, Wd1b, TDIM, 512, KP1);
    convert_w<<<dim3(512 / 32, 256 / 32, 1),    256, 0, stream>>>(cW2, Wc2b, 512, 256, 512);
    convert_w<<<dim3(512 / 32, 256 / 32, NDOM), 256, 0, stream>>>(dW2, Wd2b, 512, 256, 512);
    convert_w<<<dim3(256 / 32, 128 / 32, 1),    256, 0, stream>>>(cW3, Wc3b, 256, 128, 256);
    convert_w<<<dim3(256 / 32, 128 / 32, NDOM), 256, 0, stream>>>(dW3, Wd3b, 256, 128, 256);

    prep_kernel<<<BATCH, 256, 0, stream>>>(x, dom, pnw, pnb, demb, crw, crb,
                                           aW1, ab1, aW2, ab2, perm, XCb, auxg);

    const int GY = 32 + NDOM * 32;
    // L1: (B x 1088) @ -> 512, relu, bf16 out
    gemm_mfma<<<dim3(512 / 64, GY), 256, 0, stream>>>(
        XCb, XCb, KP1, Wc1b, Wd1b, cb1, db1, H1c, H1d, (float*)nullptr, (float*)nullptr,
        starts, KP1, 512, 1, 1);
    // L2: (B x 512) -> 256, relu, bf16 out
    gemm_mfma<<<dim3(256 / 64, GY), 256, 0, stream>>>(
        H1c, H1d, 512, Wc2b, Wd2b, cb2, db2, H2c, H2d, (float*)nullptr, (float*)nullptr,
        starts, 512, 256, 1, 1);
    // L3: (B x 256) -> 128, no relu, fp32 out
    gemm_mfma<<<dim3(128 / 64, GY), 256, 0, stream>>>(
        H2c, H2d, 256, Wc3b, Wd3b, cb3, db3, (unsigned short*)nullptr, (unsigned short*)nullptr,
        H3c, H3d, starts, 256, 128, 0, 0);

    final_kernel<<<BATCH / 4, 256, 0, stream>>>(H3c, H3d, fW1, fb1, fW2, fb2,
                                                auxg, perm, out);
}

// Round 4
// 241.829 us; speedup vs baseline: 1.9982x; 1.0333x over previous
//
#include <hip/hip_runtime.h>
#include <math.h>

#define BATCH 4096
#define FEAT  1024
#define EDIM  16
#define NDOM  8
#define TDIM  1040   // FEAT + EDIM
#define KP1   1088   // TDIM padded to multiple of 64
#define NLAYER 3
#define EPSV  1e-5f

typedef __attribute__((ext_vector_type(8))) short bf16x8;
typedef __attribute__((ext_vector_type(4))) float f32x4;

__device__ __forceinline__ unsigned short f2bf(float f) {
    union { float f; unsigned int u; } v; v.f = f;
    unsigned int u = v.u;
    return (unsigned short)((u + 0x7fffu + ((u >> 16) & 1u)) >> 16);
}
__device__ __forceinline__ float bf2f(unsigned short u) {
    union { unsigned int u; float f; } v; v.u = ((unsigned int)u) << 16; return v.f;
}

// ======== fused: 6 weight-transpose/convert segments + domain grouping, one launch ========
// blocks [0,6336): convert tiles; block 6336: histogram+scatter grouping.
__global__ __launch_bounds__(256) void convert_group(
    const int* __restrict__ dom, int* __restrict__ perm, int* __restrict__ starts,
    const float* __restrict__ cW1, const float* __restrict__ dW1,
    const float* __restrict__ cW2, const float* __restrict__ dW2,
    const float* __restrict__ cW3, const float* __restrict__ dW3,
    unsigned short* __restrict__ Wc1b, unsigned short* __restrict__ Wd1b,
    unsigned short* __restrict__ Wc2b, unsigned short* __restrict__ Wd2b,
    unsigned short* __restrict__ Wc3b, unsigned short* __restrict__ Wd3b) {
    __shared__ float tile[32][33];
    __shared__ int cnt[NDOM];
    __shared__ int off[NDOM];
    int b = blockIdx.x;
    int t = threadIdx.x;

    if (b >= 6336) {
        if (t < NDOM) cnt[t] = 0;
        __syncthreads();
        for (int i = t; i < BATCH; i += 256) atomicAdd(&cnt[dom[i]], 1);
        __syncthreads();
        if (t == 0) {
            int s = 0;
            for (int d = 0; d < NDOM; d++) { off[d] = s; starts[d] = s; s += cnt[d]; }
            starts[NDOM] = s;
        }
        __syncthreads();
        for (int i = t; i < BATCH; i += 256) {
            int p = atomicAdd(&off[dom[i]], 1);
            perm[p] = i;
        }
        return;
    }

    const float* src; unsigned short* dst; int K, N, Kp, rr;
    if (b < 544)       { src = cW1; dst = Wc1b; K = TDIM; N = 512; Kp = KP1; rr = b; }
    else if (b < 4896) { int r = b - 544; int z = r / 544; rr = r % 544;
                         src = dW1 + (size_t)z * TDIM * 512; dst = Wd1b + (size_t)z * 512 * KP1;
                         K = TDIM; N = 512; Kp = KP1; }
    else if (b < 5024) { src = cW2; dst = Wc2b; K = 512; N = 256; Kp = 512; rr = b - 4896; }
    else if (b < 6048) { int r = b - 5024; int z = r / 128; rr = r % 128;
                         src = dW2 + (size_t)z * 512 * 256; dst = Wd2b + (size_t)z * 256 * 512;
                         K = 512; N = 256; Kp = 512; }
    else if (b < 6080) { src = cW3; dst = Wc3b; K = 256; N = 128; Kp = 256; rr = b - 6048; }
    else               { int r = b - 6080; int z = r / 32; rr = r % 32;
                         src = dW3 + (size_t)z * 256 * 128; dst = Wd3b + (size_t)z * 128 * 256;
                         K = 256; N = 128; Kp = 256; }
    int tk = Kp / 32;
    int kb = rr % tk, nb = rr / tk;
    int tx = t & 31, ty = t >> 5;
    int k0 = kb * 32, n0 = nb * 32;
    #pragma unroll
    for (int i = 0; i < 4; i++) {
        int k = k0 + ty + i * 8;
        tile[ty + i * 8][tx] = (k < K) ? src[(size_t)k * N + n0 + tx] : 0.f;
    }
    __syncthreads();
    #pragma unroll
    for (int i = 0; i < 4; i++) {
        int n = n0 + ty + i * 8;
        dst[(size_t)n * Kp + k0 + tx] = f2bf(tile[tx][ty + i * 8]);
    }
}

// ------- per-row: LayerNorm + domain affine + concat + cross net + aux net -------
__global__ __launch_bounds__(256) void prep_kernel(
    const float* __restrict__ x, const int* __restrict__ dom,
    const float* __restrict__ pnw, const float* __restrict__ pnb,
    const float* __restrict__ demb,
    const float* __restrict__ crw, const float* __restrict__ crb,
    const float* __restrict__ aW1, const float* __restrict__ ab1,
    const float* __restrict__ aW2, const float* __restrict__ ab2,
    const int* __restrict__ perm,
    unsigned short* __restrict__ XCb, float* __restrict__ auxg) {
    __shared__ float x0s[TDIM];
    __shared__ float xcs[TDIM];
    __shared__ float redS[4];
    __shared__ float redQ[4];
    __shared__ float sMean, sRstd;

    int p = blockIdx.x;
    int row = perm[p];
    int d = dom[row];
    int t = threadIdx.x;

    float4 v = *(const float4*)(x + (size_t)row * FEAT + 4 * t);
    float s  = v.x + v.y + v.z + v.w;
    float ss = v.x*v.x + v.y*v.y + v.z*v.z + v.w*v.w;
    #pragma unroll
    for (int o = 32; o > 0; o >>= 1) {
        s  += __shfl_down(s,  o);
        ss += __shfl_down(ss, o);
    }
    if ((t & 63) == 0) { redS[t >> 6] = s; redQ[t >> 6] = ss; }
    __syncthreads();
    if (t == 0) {
        float S = redS[0] + redS[1] + redS[2] + redS[3];
        float Q = redQ[0] + redQ[1] + redQ[2] + redQ[3];
        float mean = S / (float)FEAT;
        float var  = Q / (float)FEAT - mean * mean;
        sMean = mean;
        sRstd = rsqrtf(var + EPSV);
    }
    __syncthreads();
    float mean = sMean, rstd = sRstd;

    float4 wv = *(const float4*)(pnw + (size_t)d * FEAT + 4 * t);
    float4 bv = *(const float4*)(pnb + (size_t)d * FEAT + 4 * t);
    {
        float n0 = (v.x - mean) * rstd * wv.x + bv.x;
        float n1 = (v.y - mean) * rstd * wv.y + bv.y;
        float n2 = (v.z - mean) * rstd * wv.z + bv.z;
        float n3 = (v.w - mean) * rstd * wv.w + bv.w;
        int j = 4 * t;
        x0s[j+0] = n0; x0s[j+1] = n1; x0s[j+2] = n2; x0s[j+3] = n3;
        xcs[j+0] = n0; xcs[j+1] = n1; xcs[j+2] = n2; xcs[j+3] = n3;
    }
    if (t < EDIM) {
        float e = demb[d * EDIM + t];
        x0s[FEAT + t] = e;
        xcs[FEAT + t] = e;
    }
    __syncthreads();

    for (int l = 0; l < NLAYER; l++) {
        float partial = 0.f;
        for (int j = t; j < TDIM; j += 256) partial += xcs[j] * crw[l * TDIM + j];
        #pragma unroll
        for (int o = 32; o > 0; o >>= 1) partial += __shfl_down(partial, o);
        if ((t & 63) == 0) redS[t >> 6] = partial;
        __syncthreads();
        float proj = redS[0] + redS[1] + redS[2] + redS[3];
        for (int j = t; j < TDIM; j += 256)
            xcs[j] = x0s[j] * proj + crb[l * TDIM + j] + xcs[j];
        __syncthreads();
    }

    // vectorized bf16 store of permuted xc row, zero-padded to KP1
    for (int j = 4 * t; j < KP1; j += 1024) {
        ushort4 sv;
        sv.x = (j + 0 < TDIM) ? f2bf(xcs[j + 0]) : 0;
        sv.y = (j + 1 < TDIM) ? f2bf(xcs[j + 1]) : 0;
        sv.z = (j + 2 < TDIM) ? f2bf(xcs[j + 2]) : 0;
        sv.w = (j + 3 < TDIM) ? f2bf(xcs[j + 3]) : 0;
        *(ushort4*)(XCb + (size_t)p * KP1 + j) = sv;
    }

    if (t < 32) {
        float h = ab1[t];
        #pragma unroll
        for (int e = 0; e < EDIM; e++) h += x0s[FEAT + e] * aW1[e * 32 + t];
        h = fmaxf(h, 0.f);
        float c = h * aW2[t];
        #pragma unroll
        for (int o = 16; o > 0; o >>= 1) c += __shfl_down(c, o, 32);
        if (t == 0) auxg[p] = c + ab2[0];
    }
}

// ---------------- MFMA bf16 GEMM, fused center+domain (layers 1,2) ----------------
__global__ __launch_bounds__(256) void gemm_mfma(
    const unsigned short* __restrict__ Ac, const unsigned short* __restrict__ Ad, int lda,
    const unsigned short* __restrict__ Wc, const unsigned short* __restrict__ Wd,
    const float* __restrict__ bc, const float* __restrict__ bd,
    unsigned short* __restrict__ Cbc, unsigned short* __restrict__ Cbd,
    const int* __restrict__ starts,
    int Kp, int N, int relu) {
    __shared__ short As[128 * 64];
    __shared__ short Bs[64 * 64];

    const unsigned short* A; const unsigned short* W; const float* bias;
    unsigned short* Cb;
    int m0, mEnd;
    int y = blockIdx.y;
    if (y < 32) {
        A = Ac; W = Wc; bias = bc; Cb = Cbc;
        m0 = y * 128; mEnd = BATCH;
    } else {
        int yy = y - 32;
        int d = yy >> 5, sl = yy & 31;
        int ds = starts[d], de = starts[d + 1];
        m0 = ds + sl * 128;
        if (m0 >= de) return;
        mEnd = de;
        A = Ad; W = Wd + (size_t)d * N * Kp; bias = bd + d * N; Cb = Cbd;
    }
    int n0 = blockIdx.x * 64;
    int tid = threadIdx.x;
    int w = tid >> 6, lane = tid & 63;
    int wm = w >> 1, wn = w & 1;
    int lr = lane & 15, q = lane >> 4;

    f32x4 acc[4][2];
    #pragma unroll
    for (int i = 0; i < 4; i++)
        #pragma unroll
        for (int j = 0; j < 2; j++)
            acc[i][j] = (f32x4){0.f, 0.f, 0.f, 0.f};

    const uint4 zero16 = make_uint4(0u, 0u, 0u, 0u);

    for (int k0 = 0; k0 < Kp; k0 += 64) {
        #pragma unroll
        for (int i = 0; i < 4; i++) {
            int flat = tid + i * 256;
            int m = flat >> 3, c = flat & 7;
            int row = m0 + m;
            uint4 val = (row < mEnd)
                ? *(const uint4*)(A + (size_t)row * lda + k0 + c * 8)
                : zero16;
            *(uint4*)(As + m * 64 + ((c ^ (m & 7)) * 8)) = val;
        }
        #pragma unroll
        for (int i = 0; i < 2; i++) {
            int flat = tid + i * 256;
            int n = flat >> 3, c = flat & 7;
            uint4 val = *(const uint4*)(W + (size_t)(n0 + n) * Kp + k0 + c * 8);
            *(uint4*)(Bs + n * 64 + ((c ^ (n & 7)) * 8)) = val;
        }
        __syncthreads();

        #pragma unroll
        for (int g = 0; g < 2; g++) {
            int c = g * 4 + q;
            bf16x8 af[4], bf[2];
            #pragma unroll
            for (int i = 0; i < 4; i++) {
                int m = wm * 64 + i * 16 + lr;
                af[i] = *(const bf16x8*)(As + m * 64 + ((c ^ (m & 7)) * 8));
            }
            #pragma unroll
            for (int j = 0; j < 2; j++) {
                int n = wn * 32 + j * 16 + lr;
                bf[j] = *(const bf16x8*)(Bs + n * 64 + ((c ^ (n & 7)) * 8));
            }
            #pragma unroll
            for (int i = 0; i < 4; i++)
                #pragma unroll
                for (int j = 0; j < 2; j++)
                    acc[i][j] = __builtin_amdgcn_mfma_f32_16x16x32_bf16(
                        af[i], bf[j], acc[i][j], 0, 0, 0);
        }
        __syncthreads();
    }

    #pragma unroll
    for (int i = 0; i < 4; i++) {
        #pragma unroll
        for (int j = 0; j < 2; j++) {
            int col = n0 + wn * 32 + j * 16 + lr;
            float bv = bias[col];
            int rowb = m0 + wm * 64 + i * 16 + q * 4;
            #pragma unroll
            for (int r = 0; r < 4; r++) {
                int row = rowb + r;
                if (row >= mEnd) continue;
                float val = acc[i][j][r] + bv;
                if (relu) val = fmaxf(val, 0.f);
                Cb[(size_t)row * N + col] = f2bf(val);
            }
        }
    }
}

// ======== fused layer-3: both chains' GEMM + STAR tanh + final MLP (MFMA) + sigmoid ========
// grid: NDOM*64 blocks, each covering up to 64 rows of one domain (slots partition all rows).
__global__ __launch_bounds__(256) void gemm3_final(
    const unsigned short* __restrict__ Ac, const unsigned short* __restrict__ Ad,
    const unsigned short* __restrict__ Wc, const unsigned short* __restrict__ Wd,
    const float* __restrict__ bc, const float* __restrict__ bd,
    const float* __restrict__ fW1, const float* __restrict__ fb1,
    const float* __restrict__ fW2, const float* __restrict__ fb2,
    const float* __restrict__ auxg, const int* __restrict__ perm,
    const int* __restrict__ starts, float* __restrict__ out) {
    __shared__ __align__(16) char smem[40960];
    short* As     = (short*)smem;            // [64][64]  8KB (XOR-swizzled chunks)
    short* Bs     = (short*)(smem + 8192);   // [128][64] 16KB
    short* fusedB = (short*)(smem + 24576);  // [64][128] 16KB bf16, swizzled

    int y = blockIdx.x;
    int d = y >> 6, sl = y & 63;
    int ds = starts[d], de = starts[d + 1];
    int m0 = ds + sl * 64;
    if (m0 >= de) return;
    int mEnd = de;

    int tid = threadIdx.x;
    int w = tid >> 6, lane = tid & 63;
    int wm = w >> 1, wn = w & 1;
    int lr = lane & 15, q = lane >> 4;
    const uint4 zero16 = make_uint4(0u, 0u, 0u, 0u);

    for (int chain = 0; chain < 2; chain++) {
        const unsigned short* A = chain ? Ad : Ac;
        const unsigned short* W = chain ? (Wd + (size_t)d * 128 * 256) : Wc;
        const float* bias = chain ? (bd + d * 128) : bc;
        f32x4 acc[2][4];
        #pragma unroll
        for (int i = 0; i < 2; i++)
            #pragma unroll
            for (int j = 0; j < 4; j++) acc[i][j] = (f32x4){0.f, 0.f, 0.f, 0.f};

        for (int k0 = 0; k0 < 256; k0 += 64) {
            #pragma unroll
            for (int i = 0; i < 2; i++) {
                int flat = tid + i * 256;
                int m = flat >> 3, c = flat & 7;
                int row = m0 + m;
                uint4 val = (row < mEnd)
                    ? *(const uint4*)(A + (size_t)row * 256 + k0 + c * 8) : zero16;
                *(uint4*)(As + m * 64 + ((c ^ (m & 7)) * 8)) = val;
            }
            #pragma unroll
            for (int i = 0; i < 4; i++) {
                int flat = tid + i * 256;
                int n = flat >> 3, c = flat & 7;
                uint4 val = *(const uint4*)(W + (size_t)n * 256 + k0 + c * 8);
                *(uint4*)(Bs + n * 64 + ((c ^ (n & 7)) * 8)) = val;
            }
            __syncthreads();
            #pragma unroll
            for (int g = 0; g < 2; g++) {
                int c = g * 4 + q;
                bf16x8 af[2], bf[4];
                #pragma unroll
                for (int i = 0; i < 2; i++) {
                    int m = wm * 32 + i * 16 + lr;
                    af[i] = *(const bf16x8*)(As + m * 64 + ((c ^ (m & 7)) * 8));
                }
                #pragma unroll
                for (int j = 0; j < 4; j++) {
                    int n = wn * 64 + j * 16 + lr;
                    bf[j] = *(const bf16x8*)(Bs + n * 64 + ((c ^ (n & 7)) * 8));
                }
                #pragma unroll
                for (int i = 0; i < 2; i++)
                    #pragma unroll
                    for (int j = 0; j < 4; j++)
                        acc[i][j] = __builtin_amdgcn_mfma_f32_16x16x32_bf16(
                            af[i], bf[j], acc[i][j], 0, 0, 0);
            }
            __syncthreads();
        }
        // epilogue into fusedB (same thread owns same (row,col) in both chains)
        #pragma unroll
        for (int i = 0; i < 2; i++) {
            #pragma unroll
            for (int j = 0; j < 4; j++) {
                int col = wn * 64 + j * 16 + lr;
                float bv = bias[col];
                int cch = col >> 3;
                #pragma unroll
                for (int r = 0; r < 4; r++) {
                    int row = wm * 32 + i * 16 + q * 4 + r;
                    int pc = (cch & 8) | ((cch ^ (row & 7)) & 7);
                    int idx = row * 128 + pc * 8 + (col & 7);
                    if (chain == 0) {
                        fusedB[idx] = (short)f2bf(acc[i][j][r] + bv);
                    } else {
                        float cv = bf2f((unsigned short)fusedB[idx]);
                        fusedB[idx] = (short)f2bf(cv * tanhf(acc[i][j][r] + bv));
                    }
                }
            }
        }
    }
    __syncthreads();

    // stage fW1 (128k x 64n fp32) -> Bsf[n][k] bf16 swizzled (aliases Bs region)
    short* Bsf = Bs;
    float* Ls  = (float*)As;
    for (int s2 = tid; s2 < 1024; s2 += 256) {
        int n = s2 >> 4, cch = s2 & 15;
        bf16x8 vv;
        #pragma unroll
        for (int kk = 0; kk < 8; kk++)
            vv[kk] = (short)f2bf(fW1[(cch * 8 + kk) * 64 + n]);
        int pc = (cch & 8) | ((cch ^ (n & 7)) & 7);
        *(bf16x8*)(Bsf + n * 128 + pc * 8) = vv;
    }
    __syncthreads();

    // final MLP layer 1 via MFMA: (64 rows x 128) @ (128 x 64)
    f32x4 acc2[2][2];
    #pragma unroll
    for (int i = 0; i < 2; i++)
        #pragma unroll
        for (int j = 0; j < 2; j++) acc2[i][j] = (f32x4){0.f, 0.f, 0.f, 0.f};
    #pragma unroll
    for (int g = 0; g < 4; g++) {
        int c = g * 4 + q;
        bf16x8 af[2], bf[2];
        #pragma unroll
        for (int i = 0; i < 2; i++) {
            int m = wm * 32 + i * 16 + lr;
            int pc = (c & 8) | ((c ^ (m & 7)) & 7);
            af[i] = *(const bf16x8*)(fusedB + m * 128 + pc * 8);
        }
        #pragma unroll
        for (int j = 0; j < 2; j++) {
            int n = wn * 32 + j * 16 + lr;
            int pc = (c & 8) | ((c ^ (n & 7)) & 7);
            bf[j] = *(const bf16x8*)(Bsf + n * 128 + pc * 8);
        }
        #pragma unroll
        for (int i = 0; i < 2; i++)
            #pragma unroll
            for (int j = 0; j < 2; j++)
                acc2[i][j] = __builtin_amdgcn_mfma_f32_16x16x32_bf16(
                    af[i], bf[j], acc2[i][j], 0, 0, 0);
    }

    float w2v[2], b1v[2];
    #pragma unroll
    for (int j = 0; j < 2; j++) {
        int col = wn * 32 + j * 16 + lr;
        w2v[j] = fW2[col];
        b1v[j] = fb1[col];
    }
    float rowv[2][4];
    #pragma unroll
    for (int i = 0; i < 2; i++)
        #pragma unroll
        for (int r = 0; r < 4; r++) {
            float v = 0.f;
            #pragma unroll
            for (int j = 0; j < 2; j++)
                v += fmaxf(acc2[i][j][r] + b1v[j], 0.f) * w2v[j];
            v += __shfl_xor(v, 1);
            v += __shfl_xor(v, 2);
            v += __shfl_xor(v, 4);
            v += __shfl_xor(v, 8);
            rowv[i][r] = v;
        }
    if (wn == 0 && lr == 0) {
        #pragma unroll
        for (int i = 0; i < 2; i++)
            #pragma unroll
            for (int r = 0; r < 4; r++)
                Ls[wm * 32 + i * 16 + q * 4 + r] = rowv[i][r];
    }
    __syncthreads();
    if (wn == 1 && lr == 0) {
        float b2 = fb2[0];
        #pragma unroll
        for (int i = 0; i < 2; i++)
            #pragma unroll
            for (int r = 0; r < 4; r++) {
                int row = wm * 32 + i * 16 + q * 4 + r;
                int p = m0 + row;
                if (p < mEnd) {
                    float logit = Ls[row] + rowv[i][r] + b2 + auxg[p];
                    out[perm[p]] = 1.f / (1.f + expf(-logit));
                }
            }
    }
}

extern "C" void kernel_launch(void* const* d_in, const int* in_sizes, int n_in,
                              void* d_out, int out_size, void* d_ws, size_t ws_size,
                              hipStream_t stream) {
    (void)in_sizes; (void)n_in; (void)out_size; (void)ws_size;

    const float* x    = (const float*)d_in[0];
    const int*   dom  = (const int*)  d_in[1];
    const float* pnw  = (const float*)d_in[2];
    const float* pnb  = (const float*)d_in[3];
    const float* demb = (const float*)d_in[4];
    const float* crw  = (const float*)d_in[5];
    const float* crb  = (const float*)d_in[6];
    const float* cW1  = (const float*)d_in[7];
    const float* cb1  = (const float*)d_in[8];
    const float* cW2  = (const float*)d_in[9];
    const float* cb2  = (const float*)d_in[10];
    const float* cW3  = (const float*)d_in[11];
    const float* cb3  = (const float*)d_in[12];
    const float* dW1  = (const float*)d_in[13];
    const float* db1  = (const float*)d_in[14];
    const float* dW2  = (const float*)d_in[15];
    const float* db2  = (const float*)d_in[16];
    const float* dW3  = (const float*)d_in[17];
    const float* db3  = (const float*)d_in[18];
    const float* fW1  = (const float*)d_in[19];
    const float* fb1  = (const float*)d_in[20];
    const float* fW2  = (const float*)d_in[21];
    const float* fb2  = (const float*)d_in[22];
    const float* aW1  = (const float*)d_in[23];
    const float* ab1  = (const float*)d_in[24];
    const float* aW2  = (const float*)d_in[25];
    const float* ab2  = (const float*)d_in[26];
    float* out = (float*)d_out;

    char* base = (char*)d_ws;
    size_t o = 0;
    auto alloc = [&](size_t bytes) { char* p = base + o; o += (bytes + 255) & ~size_t(255); return p; };

    int* perm   = (int*)alloc(BATCH * 4);
    int* starts = (int*)alloc((NDOM + 1) * 4);
    float* auxg = (float*)alloc(BATCH * 4);
    unsigned short* XCb  = (unsigned short*)alloc((size_t)BATCH * KP1 * 2);
    unsigned short* H1c  = (unsigned short*)alloc((size_t)BATCH * 512 * 2);
    unsigned short* H1d  = (unsigned short*)alloc((size_t)BATCH * 512 * 2);
    unsigned short* H2c  = (unsigned short*)alloc((size_t)BATCH * 256 * 2);
    unsigned short* H2d  = (unsigned short*)alloc((size_t)BATCH * 256 * 2);
    unsigned short* Wc1b = (unsigned short*)alloc((size_t)512 * KP1 * 2);
    unsigned short* Wd1b = (unsigned short*)alloc((size_t)NDOM * 512 * KP1 * 2);
    unsigned short* Wc2b = (unsigned short*)alloc((size_t)256 * 512 * 2);
    unsigned short* Wd2b = (unsigned short*)alloc((size_t)NDOM * 256 * 512 * 2);
    unsigned short* Wc3b = (unsigned short*)alloc((size_t)128 * 256 * 2);
    unsigned short* Wd3b = (unsigned short*)alloc((size_t)NDOM * 128 * 256 * 2);

    convert_group<<<6337, 256, 0, stream>>>(dom, perm, starts,
                                            cW1, dW1, cW2, dW2, cW3, dW3,
                                            Wc1b, Wd1b, Wc2b, Wd2b, Wc3b, Wd3b);

    prep_kernel<<<BATCH, 256, 0, stream>>>(x, dom, pnw, pnb, demb, crw, crb,
                                           aW1, ab1, aW2, ab2, perm, XCb, auxg);

    const int GY = 32 + NDOM * 32;
    gemm_mfma<<<dim3(512 / 64, GY), 256, 0, stream>>>(
        XCb, XCb, KP1, Wc1b, Wd1b, cb1, db1, H1c, H1d, starts, KP1, 512, 1);
    gemm_mfma<<<dim3(256 / 64, GY), 256, 0, stream>>>(
        H1c, H1d, 512, Wc2b, Wd2b, cb2, db2, H2c, H2d, starts, 512, 256, 1);

    gemm3_final<<<NDOM * 64, 256, 0, stream>>>(
        H2c, H2d, Wc3b, Wd3b, cb3, db3, fW1, fb1, fW2, fb2,
        auxg, perm, starts, out);
}

// Round 6
// 226.119 us; speedup vs baseline: 2.1370x; 1.0695x over previous
//
#include <hip/hip_runtime.h>
#include <math.h>
#include <stdint.h>

#define BATCH 4096
#define FEAT  1024
#define EDIM  16
#define NDOM  8
#define TDIM  1040   // FEAT + EDIM
#define KP1   1088   // TDIM padded to multiple of 64
#define NLAYER 3
#define EPSV  1e-5f

typedef __attribute__((ext_vector_type(8))) short bf16x8;
typedef __attribute__((ext_vector_type(4))) float f32x4;

__device__ __forceinline__ unsigned short f2bf(float f) {
    union { float f; unsigned int u; } v; v.f = f;
    unsigned int u = v.u;
    return (unsigned short)((u + 0x7fffu + ((u >> 16) & 1u)) >> 16);
}
__device__ __forceinline__ float bf2f(unsigned short u) {
    union { unsigned int u; float f; } v; v.u = ((unsigned int)u) << 16; return v.f;
}
__device__ __forceinline__ void gload_lds16(const void* g, void* l) {
    __builtin_amdgcn_global_load_lds(
        (const __attribute__((address_space(1))) void*)(g),
        (__attribute__((address_space(3))) void*)(l), 16, 0, 0);
}

// ======== fused front: grouping (block 0) + weight converts (1..6336) + prep (6337..) ========
__global__ __launch_bounds__(256) void fused_front(
    const int* __restrict__ dom, int* __restrict__ perm, int* __restrict__ starts,
    const float* __restrict__ cW1, const float* __restrict__ dW1,
    const float* __restrict__ cW2, const float* __restrict__ dW2,
    const float* __restrict__ cW3, const float* __restrict__ dW3,
    unsigned short* __restrict__ Wc1b, unsigned short* __restrict__ Wd1b,
    unsigned short* __restrict__ Wc2b, unsigned short* __restrict__ Wd2b,
    unsigned short* __restrict__ Wc3b, unsigned short* __restrict__ Wd3b,
    const float* __restrict__ x,
    const float* __restrict__ pnw, const float* __restrict__ pnb,
    const float* __restrict__ demb,
    const float* __restrict__ crw, const float* __restrict__ crb,
    const float* __restrict__ aW1, const float* __restrict__ ab1,
    const float* __restrict__ aW2, const float* __restrict__ ab2,
    unsigned short* __restrict__ XCb, float* __restrict__ auxg) {
    int b = blockIdx.x;
    int t = threadIdx.x;

    if (b == 0) {
        // ---- grouping: histogram + scatter ----
        __shared__ int cnt[NDOM];
        __shared__ int off[NDOM];
        if (t < NDOM) cnt[t] = 0;
        __syncthreads();
        for (int i = t; i < BATCH; i += 256) atomicAdd(&cnt[dom[i]], 1);
        __syncthreads();
        if (t == 0) {
            int s = 0;
            for (int d = 0; d < NDOM; d++) { off[d] = s; starts[d] = s; s += cnt[d]; }
            starts[NDOM] = s;
        }
        __syncthreads();
        for (int i = t; i < BATCH; i += 256) {
            int p = atomicAdd(&off[dom[i]], 1);
            perm[p] = i;
        }
        return;
    }
    if (b <= 6336) {
        // ---- weight convert: fp32 (K,N) -> bf16 (N,Kp), zero-pad ----
        __shared__ float tile[32][33];
        int bb = b - 1;
        const float* src; unsigned short* dst; int K, N, Kp, rr;
        if (bb < 544)       { src = cW1; dst = Wc1b; K = TDIM; N = 512; Kp = KP1; rr = bb; }
        else if (bb < 4896) { int r = bb - 544; int z = r / 544; rr = r % 544;
                              src = dW1 + (size_t)z * TDIM * 512; dst = Wd1b + (size_t)z * 512 * KP1;
                              K = TDIM; N = 512; Kp = KP1; }
        else if (bb < 5024) { src = cW2; dst = Wc2b; K = 512; N = 256; Kp = 512; rr = bb - 4896; }
        else if (bb < 6048) { int r = bb - 5024; int z = r / 128; rr = r % 128;
                              src = dW2 + (size_t)z * 512 * 256; dst = Wd2b + (size_t)z * 256 * 512;
                              K = 512; N = 256; Kp = 512; }
        else if (bb < 6080) { src = cW3; dst = Wc3b; K = 256; N = 128; Kp = 256; rr = bb - 6048; }
        else                { int r = bb - 6080; int z = r / 32; rr = r % 32;
                              src = dW3 + (size_t)z * 256 * 128; dst = Wd3b + (size_t)z * 128 * 256;
                              K = 256; N = 128; Kp = 256; }
        int tk = Kp / 32;
        int kb = rr % tk, nb = rr / tk;
        int tx = t & 31, ty = t >> 5;
        int k0 = kb * 32, n0 = nb * 32;
        #pragma unroll
        for (int i = 0; i < 4; i++) {
            int k = k0 + ty + i * 8;
            tile[ty + i * 8][tx] = (k < K) ? src[(size_t)k * N + n0 + tx] : 0.f;
        }
        __syncthreads();
        #pragma unroll
        for (int i = 0; i < 4; i++) {
            int n = n0 + ty + i * 8;
            dst[(size_t)n * Kp + k0 + tx] = f2bf(tile[tx][ty + i * 8]);
        }
        return;
    }

    // ---- prep: LayerNorm + domain affine + concat + cross net + aux net (unpermuted row) ----
    __shared__ float x0s[TDIM];
    __shared__ float xcs[TDIM];
    __shared__ float redS[4];
    __shared__ float redQ[4];
    __shared__ float sMean, sRstd;

    int row = b - 6337;
    int d = dom[row];

    float4 v = *(const float4*)(x + (size_t)row * FEAT + 4 * t);
    float s  = v.x + v.y + v.z + v.w;
    float ss = v.x*v.x + v.y*v.y + v.z*v.z + v.w*v.w;
    #pragma unroll
    for (int o = 32; o > 0; o >>= 1) {
        s  += __shfl_down(s,  o);
        ss += __shfl_down(ss, o);
    }
    if ((t & 63) == 0) { redS[t >> 6] = s; redQ[t >> 6] = ss; }
    __syncthreads();
    if (t == 0) {
        float S = redS[0] + redS[1] + redS[2] + redS[3];
        float Q = redQ[0] + redQ[1] + redQ[2] + redQ[3];
        float mean = S / (float)FEAT;
        float var  = Q / (float)FEAT - mean * mean;
        sMean = mean;
        sRstd = rsqrtf(var + EPSV);
    }
    __syncthreads();
    float mean = sMean, rstd = sRstd;

    float4 wv = *(const float4*)(pnw + (size_t)d * FEAT + 4 * t);
    float4 bv = *(const float4*)(pnb + (size_t)d * FEAT + 4 * t);
    {
        float n0 = (v.x - mean) * rstd * wv.x + bv.x;
        float n1 = (v.y - mean) * rstd * wv.y + bv.y;
        float n2 = (v.z - mean) * rstd * wv.z + bv.z;
        float n3 = (v.w - mean) * rstd * wv.w + bv.w;
        int j = 4 * t;
        x0s[j+0] = n0; x0s[j+1] = n1; x0s[j+2] = n2; x0s[j+3] = n3;
        xcs[j+0] = n0; xcs[j+1] = n1; xcs[j+2] = n2; xcs[j+3] = n3;
    }
    if (t < EDIM) {
        float e = demb[d * EDIM + t];
        x0s[FEAT + t] = e;
        xcs[FEAT + t] = e;
    }
    __syncthreads();

    for (int l = 0; l < NLAYER; l++) {
        float partial = 0.f;
        for (int j = t; j < TDIM; j += 256) partial += xcs[j] * crw[l * TDIM + j];
        #pragma unroll
        for (int o = 32; o > 0; o >>= 1) partial += __shfl_down(partial, o);
        if ((t & 63) == 0) redS[t >> 6] = partial;
        __syncthreads();
        float proj = redS[0] + redS[1] + redS[2] + redS[3];
        for (int j = t; j < TDIM; j += 256)
            xcs[j] = x0s[j] * proj + crb[l * TDIM + j] + xcs[j];
        __syncthreads();
    }

    for (int j = 4 * t; j < KP1; j += 1024) {
        ushort4 sv;
        sv.x = (j + 0 < TDIM) ? f2bf(xcs[j + 0]) : 0;
        sv.y = (j + 1 < TDIM) ? f2bf(xcs[j + 1]) : 0;
        sv.z = (j + 2 < TDIM) ? f2bf(xcs[j + 2]) : 0;
        sv.w = (j + 3 < TDIM) ? f2bf(xcs[j + 3]) : 0;
        *(ushort4*)(XCb + (size_t)row * KP1 + j) = sv;
    }

    if (t < 32) {
        float h = ab1[t];
        #pragma unroll
        for (int e = 0; e < EDIM; e++) h += x0s[FEAT + e] * aW1[e * 32 + t];
        h = fmaxf(h, 0.f);
        float c = h * aW2[t];
        #pragma unroll
        for (int o = 16; o > 0; o >>= 1) c += __shfl_down(c, o, 32);
        if (t == 0) auxg[row] = c + ab2[0];
    }
}

// ======== MFMA bf16 GEMM v2: 128x128 tile, BK=64, global_load_lds staging ========
// A rows gathered via perm when usePerm=1 (L1). W: (N,Kp) bf16. C: permuted rows.
__global__ __launch_bounds__(256) void gemm_mfma_v2(
    const unsigned short* __restrict__ Ac, const unsigned short* __restrict__ Ad, int lda,
    const unsigned short* __restrict__ Wc, const unsigned short* __restrict__ Wd,
    const float* __restrict__ bc, const float* __restrict__ bd,
    unsigned short* __restrict__ Cc, unsigned short* __restrict__ Cd,
    const int* __restrict__ starts, const int* __restrict__ perm, int usePerm,
    int Kp, int N, int relu) {
    __shared__ short As[128 * 64];
    __shared__ short Bs[128 * 64];

    const unsigned short* A; const unsigned short* W; const float* bias;
    unsigned short* C;
    int m0, mEnd;
    int y = blockIdx.y;
    if (y < 32) {
        A = Ac; W = Wc; bias = bc; C = Cc;
        m0 = y * 128; mEnd = BATCH;
    } else {
        int yy = y - 32;
        int d = yy >> 5, sl = yy & 31;
        int ds = starts[d], de = starts[d + 1];
        m0 = ds + sl * 128;
        if (m0 >= de) return;
        mEnd = de;
        A = Ad; W = Wd + (size_t)d * N * Kp; bias = bd + d * N; C = Cd;
    }
    int n0 = blockIdx.x * 128;
    int tid = threadIdx.x;
    int w = tid >> 6, lane = tid & 63;
    int wm = w >> 1, wn = w & 1;
    int lr = lane & 15, q = lane >> 4;

    // per-issue staging pointers (source XOR-swizzle folded in; dest lane-ordered)
    const unsigned short* pA[4]; const unsigned short* pB[4];
    short* dA[4]; short* dB[4];
    #pragma unroll
    for (int i = 0; i < 4; i++) {
        int seg = i * 4 + w;
        int ch = seg * 64 + lane;
        int loc = ch >> 3, c = ch & 7;
        int mm = m0 + loc; if (mm > mEnd - 1) mm = mEnd - 1;
        int row = usePerm ? perm[mm] : mm;
        pA[i] = A + (size_t)row * lda + ((c ^ (loc & 7)) << 3);
        dA[i] = As + seg * 512;
        pB[i] = W + (size_t)(n0 + loc) * Kp + ((c ^ (loc & 7)) << 3);
        dB[i] = Bs + seg * 512;
    }

    f32x4 acc[4][4];
    #pragma unroll
    for (int i = 0; i < 4; i++)
        #pragma unroll
        for (int j = 0; j < 4; j++)
            acc[i][j] = (f32x4){0.f, 0.f, 0.f, 0.f};

    for (int k0 = 0; k0 < Kp; k0 += 64) {
        #pragma unroll
        for (int i = 0; i < 4; i++) gload_lds16(pA[i] + k0, dA[i]);
        #pragma unroll
        for (int i = 0; i < 4; i++) gload_lds16(pB[i] + k0, dB[i]);
        __syncthreads();

        #pragma unroll
        for (int half = 0; half < 2; half++) {
            int c = half * 4 + q;
            bf16x8 af[4], bf[4];
            #pragma unroll
            for (int i = 0; i < 4; i++) {
                int m = wm * 64 + i * 16 + lr;
                af[i] = *(const bf16x8*)(As + m * 64 + ((c ^ (m & 7)) << 3));
            }
            #pragma unroll
            for (int j = 0; j < 4; j++) {
                int n = wn * 64 + j * 16 + lr;
                bf[j] = *(const bf16x8*)(Bs + n * 64 + ((c ^ (n & 7)) << 3));
            }
            #pragma unroll
            for (int i = 0; i < 4; i++)
                #pragma unroll
                for (int j = 0; j < 4; j++)
                    acc[i][j] = __builtin_amdgcn_mfma_f32_16x16x32_bf16(
                        af[i], bf[j], acc[i][j], 0, 0, 0);
        }
        __syncthreads();
    }

    #pragma unroll
    for (int i = 0; i < 4; i++) {
        #pragma unroll
        for (int j = 0; j < 4; j++) {
            int col = n0 + wn * 64 + j * 16 + lr;
            float bvv = bias[col];
            int rowb = m0 + wm * 64 + i * 16 + q * 4;
            #pragma unroll
            for (int r = 0; r < 4; r++) {
                int row = rowb + r;
                if (row >= mEnd) continue;
                float val = acc[i][j][r] + bvv;
                if (relu) val = fmaxf(val, 0.f);
                C[(size_t)row * N + col] = f2bf(val);
            }
        }
    }
}

// ======== fused layer-3: both chains' GEMM + STAR tanh + final MLP (MFMA) + sigmoid ========
__global__ __launch_bounds__(256) void gemm3_final(
    const unsigned short* __restrict__ Ac, const unsigned short* __restrict__ Ad,
    const unsigned short* __restrict__ Wc, const unsigned short* __restrict__ Wd,
    const float* __restrict__ bc, const float* __restrict__ bd,
    const float* __restrict__ fW1, const float* __restrict__ fb1,
    const float* __restrict__ fW2, const float* __restrict__ fb2,
    const float* __restrict__ auxg, const int* __restrict__ perm,
    const int* __restrict__ starts, float* __restrict__ out) {
    __shared__ __align__(16) char smem[40960];
    short* As     = (short*)smem;            // [64][64]  8KB
    short* Bs     = (short*)(smem + 8192);   // [128][64] 16KB
    short* fusedB = (short*)(smem + 24576);  // [64][128] 16KB bf16, swizzled

    int y = blockIdx.x;
    int d = y >> 6, sl = y & 63;
    int ds = starts[d], de = starts[d + 1];
    int m0 = ds + sl * 64;
    if (m0 >= de) return;
    int mEnd = de;

    int tid = threadIdx.x;
    int w = tid >> 6, lane = tid & 63;
    int wm = w >> 1, wn = w & 1;
    int lr = lane & 15, q = lane >> 4;
    const uint4 zero16 = make_uint4(0u, 0u, 0u, 0u);

    for (int chain = 0; chain < 2; chain++) {
        const unsigned short* A = chain ? Ad : Ac;
        const unsigned short* W = chain ? (Wd + (size_t)d * 128 * 256) : Wc;
        const float* bias = chain ? (bd + d * 128) : bc;
        f32x4 acc[2][4];
        #pragma unroll
        for (int i = 0; i < 2; i++)
            #pragma unroll
            for (int j = 0; j < 4; j++) acc[i][j] = (f32x4){0.f, 0.f, 0.f, 0.f};

        for (int k0 = 0; k0 < 256; k0 += 64) {
            #pragma unroll
            for (int i = 0; i < 2; i++) {
                int flat = tid + i * 256;
                int m = flat >> 3, c = flat & 7;
                int row = m0 + m;
                uint4 val = (row < mEnd)
                    ? *(const uint4*)(A + (size_t)row * 256 + k0 + c * 8) : zero16;
                *(uint4*)(As + m * 64 + ((c ^ (m & 7)) * 8)) = val;
            }
            #pragma unroll
            for (int i = 0; i < 4; i++) {
                int flat = tid + i * 256;
                int n = flat >> 3, c = flat & 7;
                uint4 val = *(const uint4*)(W + (size_t)n * 256 + k0 + c * 8);
                *(uint4*)(Bs + n * 64 + ((c ^ (n & 7)) * 8)) = val;
            }
            __syncthreads();
            #pragma unroll
            for (int g = 0; g < 2; g++) {
                int c = g * 4 + q;
                bf16x8 af[2], bf[4];
                #pragma unroll
                for (int i = 0; i < 2; i++) {
                    int m = wm * 32 + i * 16 + lr;
                    af[i] = *(const bf16x8*)(As + m * 64 + ((c ^ (m & 7)) * 8));
                }
                #pragma unroll
                for (int j = 0; j < 4; j++) {
                    int n = wn * 64 + j * 16 + lr;
                    bf[j] = *(const bf16x8*)(Bs + n * 64 + ((c ^ (n & 7)) * 8));
                }
                #pragma unroll
                for (int i = 0; i < 2; i++)
                    #pragma unroll
                    for (int j = 0; j < 4; j++)
                        acc[i][j] = __builtin_amdgcn_mfma_f32_16x16x32_bf16(
                            af[i], bf[j], acc[i][j], 0, 0, 0);
            }
            __syncthreads();
        }
        #pragma unroll
        for (int i = 0; i < 2; i++) {
            #pragma unroll
            for (int j = 0; j < 4; j++) {
                int col = wn * 64 + j * 16 + lr;
                float bvv = bias[col];
                int cch = col >> 3;
                #pragma unroll
                for (int r = 0; r < 4; r++) {
                    int row = wm * 32 + i * 16 + q * 4 + r;
                    int pc = (cch & 8) | ((cch ^ (row & 7)) & 7);
                    int idx = row * 128 + pc * 8 + (col & 7);
                    if (chain == 0) {
                        fusedB[idx] = (short)f2bf(acc[i][j][r] + bvv);
                    } else {
                        float cv = bf2f((unsigned short)fusedB[idx]);
                        fusedB[idx] = (short)f2bf(cv * tanhf(acc[i][j][r] + bvv));
                    }
                }
            }
        }
    }
    __syncthreads();

    short* Bsf = Bs;
    float* Ls  = (float*)As;
    for (int s2 = tid; s2 < 1024; s2 += 256) {
        int n = s2 >> 4, cch = s2 & 15;
        bf16x8 vv;
        #pragma unroll
        for (int kk = 0; kk < 8; kk++)
            vv[kk] = (short)f2bf(fW1[(cch * 8 + kk) * 64 + n]);
        int pc = (cch & 8) | ((cch ^ (n & 7)) & 7);
        *(bf16x8*)(Bsf + n * 128 + pc * 8) = vv;
    }
    __syncthreads();

    f32x4 acc2[2][2];
    #pragma unroll
    for (int i = 0; i < 2; i++)
        #pragma unroll
        for (int j = 0; j < 2; j++) acc2[i][j] = (f32x4){0.f, 0.f, 0.f, 0.f};
    #pragma unroll
    for (int g = 0; g < 4; g++) {
        int c = g * 4 + q;
        bf16x8 af[2], bf[2];
        #pragma unroll
        for (int i = 0; i < 2; i++) {
            int m = wm * 32 + i * 16 + lr;
            int pc = (c & 8) | ((c ^ (m & 7)) & 7);
            af[i] = *(const bf16x8*)(fusedB + m * 128 + pc * 8);
        }
        #pragma unroll
        for (int j = 0; j < 2; j++) {
            int n = wn * 32 + j * 16 + lr;
            int pc = (c & 8) | ((c ^ (n & 7)) & 7);
            bf[j] = *(const bf16x8*)(Bsf + n * 128 + pc * 8);
        }
        #pragma unroll
        for (int i = 0; i < 2; i++)
            #pragma unroll
            for (int j = 0; j < 2; j++)
                acc2[i][j] = __builtin_amdgcn_mfma_f32_16x16x32_bf16(
                    af[i], bf[j], acc2[i][j], 0, 0, 0);
    }

    float w2v[2], b1v[2];
    #pragma unroll
    for (int j = 0; j < 2; j++) {
        int col = wn * 32 + j * 16 + lr;
        w2v[j] = fW2[col];
        b1v[j] = fb1[col];
    }
    float rowv[2][4];
    #pragma unroll
    for (int i = 0; i < 2; i++)
        #pragma unroll
        for (int r = 0; r < 4; r++) {
            float v = 0.f;
            #pragma unroll
            for (int j = 0; j < 2; j++)
                v += fmaxf(acc2[i][j][r] + b1v[j], 0.f) * w2v[j];
            v += __shfl_xor(v, 1);
            v += __shfl_xor(v, 2);
            v += __shfl_xor(v, 4);
            v += __shfl_xor(v, 8);
            rowv[i][r] = v;
        }
    if (wn == 0 && lr == 0) {
        #pragma unroll
        for (int i = 0; i < 2; i++)
            #pragma unroll
            for (int r = 0; r < 4; r++)
                Ls[wm * 32 + i * 16 + q * 4 + r] = rowv[i][r];
    }
    __syncthreads();
    if (wn == 1 && lr == 0) {
        float b2 = fb2[0];
        #pragma unroll
        for (int i = 0; i < 2; i++)
            #pragma unroll
            for (int r = 0; r < 4; r++) {
                int row = wm * 32 + i * 16 + q * 4 + r;
                int p = m0 + row;
                if (p < mEnd) {
                    int orow = perm[p];
                    float logit = Ls[row] + rowv[i][r] + b2 + auxg[orow];
                    out[orow] = 1.f / (1.f + expf(-logit));
                }
            }
    }
}

extern "C" void kernel_launch(void* const* d_in, const int* in_sizes, int n_in,
                              void* d_out, int out_size, void* d_ws, size_t ws_size,
                              hipStream_t stream) {
    (void)in_sizes; (void)n_in; (void)out_size; (void)ws_size;

    const float* x    = (const float*)d_in[0];
    const int*   dom  = (const int*)  d_in[1];
    const float* pnw  = (const float*)d_in[2];
    const float* pnb  = (const float*)d_in[3];
    const float* demb = (const float*)d_in[4];
    const float* crw  = (const float*)d_in[5];
    const float* crb  = (const float*)d_in[6];
    const float* cW1  = (const float*)d_in[7];
    const float* cb1  = (const float*)d_in[8];
    const float* cW2  = (const float*)d_in[9];
    const float* cb2  = (const float*)d_in[10];
    const float* cW3  = (const float*)d_in[11];
    const float* cb3  = (const float*)d_in[12];
    const float* dW1  = (const float*)d_in[13];
    const float* db1  = (const float*)d_in[14];
    const float* dW2  = (const float*)d_in[15];
    const float* db2  = (const float*)d_in[16];
    const float* dW3  = (const float*)d_in[17];
    const float* db3  = (const float*)d_in[18];
    const float* fW1  = (const float*)d_in[19];
    const float* fb1  = (const float*)d_in[20];
    const float* fW2  = (const float*)d_in[21];
    const float* fb2  = (const float*)d_in[22];
    const float* aW1  = (const float*)d_in[23];
    const float* ab1  = (const float*)d_in[24];
    const float* aW2  = (const float*)d_in[25];
    const float* ab2  = (const float*)d_in[26];
    float* out = (float*)d_out;

    char* base = (char*)d_ws;
    size_t o = 0;
    auto alloc = [&](size_t bytes) { char* p = base + o; o += (bytes + 255) & ~size_t(255); return p; };

    int* perm   = (int*)alloc(BATCH * 4);
    int* starts = (int*)alloc((NDOM + 1) * 4);
    float* auxg = (float*)alloc(BATCH * 4);
    unsigned short* XCb  = (unsigned short*)alloc((size_t)BATCH * KP1 * 2);
    unsigned short* H1c  = (unsigned short*)alloc((size_t)BATCH * 512 * 2);
    unsigned short* H1d  = (unsigned short*)alloc((size_t)BATCH * 512 * 2);
    unsigned short* H2c  = (unsigned short*)alloc((size_t)BATCH * 256 * 2);
    unsigned short* H2d  = (unsigned short*)alloc((size_t)BATCH * 256 * 2);
    unsigned short* Wc1b = (unsigned short*)alloc((size_t)512 * KP1 * 2);
    unsigned short* Wd1b = (unsigned short*)alloc((size_t)NDOM * 512 * KP1 * 2);
    unsigned short* Wc2b = (unsigned short*)alloc((size_t)256 * 512 * 2);
    unsigned short* Wd2b = (unsigned short*)alloc((size_t)NDOM * 256 * 512 * 2);
    unsigned short* Wc3b = (unsigned short*)alloc((size_t)128 * 256 * 2);
    unsigned short* Wd3b = (unsigned short*)alloc((size_t)NDOM * 128 * 256 * 2);

    // 1) grouping + weight convert + prep (independent parts, one launch)
    fused_front<<<1 + 6336 + BATCH, 256, 0, stream>>>(
        dom, perm, starts, cW1, dW1, cW2, dW2, cW3, dW3,
        Wc1b, Wd1b, Wc2b, Wd2b, Wc3b, Wd3b,
        x, pnw, pnb, demb, crw, crb, aW1, ab1, aW2, ab2, XCb, auxg);

    // 2) L1: (4096 x 1088) -> 512, relu  (A gathered via perm)
    gemm_mfma_v2<<<dim3(512 / 128, 32 + NDOM * 32), 256, 0, stream>>>(
        XCb, XCb, KP1, Wc1b, Wd1b, cb1, db1, H1c, H1d, starts, perm, 1, KP1, 512, 1);
    // 3) L2: (4096 x 512) -> 256, relu
    gemm_mfma_v2<<<dim3(256 / 128, 32 + NDOM * 32), 256, 0, stream>>>(
        H1c, H1d, 512, Wc2b, Wd2b, cb2, db2, H2c, H2d, starts, perm, 0, 512, 256, 1);

    // 4) L3 + STAR + final MLP + sigmoid
    gemm3_final<<<NDOM * 64, 256, 0, stream>>>(
        H2c, H2d, Wc3b, Wd3b, cb3, db3, fW1, fb1, fW2, fb2,
        auxg, perm, starts, out);
}